// Round 7
// baseline (2149.883 us; speedup 1.0000x reference)
//
#include <hip/hip_runtime.h>

// ---------------------------------------------------------------------------
// TIRGRNN: 2-layer GRU-like RNN. B=128, T=128, H=1024, L=2.
// R11: R6 protocol restored exactly (proven 601us/layer), plus two deltas:
//  (1) wave-4 poller uses a 3-deep pipelined probe (counted vmcnt(4) waits
//      only the oldest slot -- the corrected form of R10's broken discipline;
//      stale probes safe on monotone flags; sched_barrier pins checks).
//  (2) Cg layout [g][os][b:68][16o x 4kh interleaved]: ew reads collapse
//      24 scalar ds_read_b32 -> 6 ds_read_b128, bank-balanced.
// Everything else identical to the 1614us R6 build (gemm_xp global_load_lds,
// 3 barriers/step, outputs+xp prefetch off the vmcnt chain).
// ---------------------------------------------------------------------------

typedef __attribute__((ext_vector_type(8))) short short8;   // 8 x bf16
typedef __attribute__((ext_vector_type(4))) float f32x4;
typedef __attribute__((ext_vector_type(4))) unsigned int u32x4;

#define BSZ   128
#define TSZ   128
#define HSZ   1024
#define R3H   3072
#define BTH   16777216   // B*T*H
#define BH    131072     // B*H
#define NWG   256

__device__ __forceinline__ float bf2f(unsigned short u) {
    unsigned x = ((unsigned)u) << 16;
    float f; __builtin_memcpy(&f, &x, 4); return f;
}
__device__ __forceinline__ unsigned short f2b(float f) {
    unsigned x; __builtin_memcpy(&x, &f, 4);
    x += 0x7fffu + ((x >> 16) & 1u);      // RNE
    return (unsigned short)(x >> 16);
}

// ---------------------------------------------------------------------------
// fp32 -> bf16 bulk convert
// ---------------------------------------------------------------------------
__global__ void cvt_bf16(const float* __restrict__ s, unsigned short* __restrict__ d, int n4) {
    int i = blockIdx.x * blockDim.x + threadIdx.x;
    int st = gridDim.x * blockDim.x;
    for (; i < n4; i += st) {
        float4 v = ((const float4*)s)[i];
        ushort4 o;
        o.x = f2b(v.x); o.y = f2b(v.y); o.z = f2b(v.z); o.w = f2b(v.w);
        ((ushort4*)d)[i] = o;
    }
}

// ---------------------------------------------------------------------------
// async 16B/lane global->LDS. LDS dest = wave-uniform base + lane*16 (HW rule);
// global src is per-lane.
// ---------------------------------------------------------------------------
__device__ __forceinline__ void gld_lds16(const unsigned short* g, unsigned short* ldsbase) {
    typedef const unsigned int __attribute__((address_space(1)))* gp_t;
    typedef unsigned int __attribute__((address_space(3)))* lp_t;
    __builtin_amdgcn_global_load_lds(
        (gp_t)(unsigned long long)(const void*)g,
        (lp_t)(unsigned)(unsigned long long)(void*)ldsbase,
        16, 0, 0);
}

// ---------------------------------------------------------------------------
// Bulk projection GEMM, transposed output:
// xp[t][b][row] = sum_k In[(b*T+t)*H+k] * W[row*H+k] + bias[row]
// m97-style staging: linear LDS [row][32 shorts], global_load_lds dwordx4.
// ---------------------------------------------------------------------------
__global__ __launch_bounds__(256) void gemm_xp(
    const unsigned short* __restrict__ A,
    const unsigned short* __restrict__ W,
    const float* __restrict__ bias,
    unsigned short* __restrict__ xp)
{
    __shared__ unsigned short Wt[128 * 32];
    __shared__ unsigned short It[128 * 32];

    const int tC  = blockIdx.x;
    const int n0  = blockIdx.y << 7;
    const int tid = threadIdx.x;
    const int lane = tid & 63, wv = tid >> 6;
    const int mh = (wv >> 1) << 6;     // b half
    const int nh = (wv & 1) << 6;      // wrow half
    const int q = lane >> 4, mm = lane & 15;

    f32x4 acc[4][4];
#pragma unroll
    for (int i = 0; i < 4; i++)
#pragma unroll
        for (int j = 0; j < 4; j++) acc[i][j] = (f32x4){0.f, 0.f, 0.f, 0.f};

    const int r_l = (wv << 5) + (lane >> 2);
    const int c8  = (lane & 3) << 3;                  // short offset in 32-short row
    const unsigned short* ag0 = &A[(r_l * TSZ + tC) * HSZ + c8];
    const unsigned short* ag1 = &A[((r_l + 16) * TSZ + tC) * HSZ + c8];
    const unsigned short* wg0 = &W[(n0 + r_l) * HSZ + c8];
    const unsigned short* wg1 = &W[(n0 + r_l + 16) * HSZ + c8];
    unsigned short* itb0 = &It[(wv << 10)];           // (wv*32 rows)*32 shorts
    unsigned short* itb1 = &It[(wv << 10) + 512];     // +16 rows
    unsigned short* wtb0 = &Wt[(wv << 10)];
    unsigned short* wtb1 = &Wt[(wv << 10) + 512];

    for (int kk = 0; kk < 32; kk++) {
        const int kb = kk << 5;
        __syncthreads();                               // prev-iter LDS reads done
        gld_lds16(ag0 + kb, itb0);
        gld_lds16(ag1 + kb, itb1);
        gld_lds16(wg0 + kb, wtb0);
        gld_lds16(wg1 + kb, wtb1);
        asm volatile("s_waitcnt vmcnt(0)" ::: "memory");
        __syncthreads();                               // all waves' LDS writes landed
        short8 af[4], bf[4];
#pragma unroll
        for (int mi = 0; mi < 4; mi++)
            af[mi] = *(const short8*)&It[((mh + mi * 16 + mm) << 5) + (q << 3)];
#pragma unroll
        for (int ni = 0; ni < 4; ni++)
            bf[ni] = *(const short8*)&Wt[((nh + ni * 16 + mm) << 5) + (q << 3)];
#pragma unroll
        for (int mi = 0; mi < 4; mi++)
#pragma unroll
            for (int ni = 0; ni < 4; ni++)
                acc[mi][ni] = __builtin_amdgcn_mfma_f32_16x16x32_bf16(af[mi], bf[ni], acc[mi][ni], 0, 0, 0);
    }

    // epilogue: D row (m)=b, col (n)=wrow; xp slab [b][3072]
    unsigned short* slab = xp + tC * (BSZ * R3H);
#pragma unroll
    for (int ni = 0; ni < 4; ni++) {
        const int wrow = n0 + nh + ni * 16 + mm;
        const float bs = bias[wrow];
#pragma unroll
        for (int mi = 0; mi < 4; mi++) {
            const int bb = mh + mi * 16 + (q << 2);
#pragma unroll
            for (int r = 0; r < 4; r++)
                slab[(bb + r) * R3H + wrow] = f2b(acc[mi][ni][r] + bs);
        }
    }
}

// ---------------------------------------------------------------------------
// Persistent recurrence kernel. 256 wgs x 768 thr (12 waves).
// wg (bt,ot): b in [bt*16,+16), o in [ot*32,+32). Only the 32 wgs sharing bt
// exchange data -> 8 independent group-local flag protocols.
// Flags: u32 per (wg, ew-wave) = 128 per group; monotonic step counters.
// Per step: wave 4 polls with a 3-deep probe pipeline -> bar -> waves 4-11
// stage h slab -> bar -> MFMA k-loop + Cg partials -> bar -> waves 0-3
// gates + h store + own-store vmcnt + per-wave flag; outputs & xp prefetch
// AFTER the flag.
// Cg layout: [3 g][2 os][16 b (stride 68 f32)][16 oi x 4 kh], so ew reads
// one f32x4 (all 4 kh partials) per (gate, o) -- 6 ds_read_b128/thread.
// ---------------------------------------------------------------------------
__global__ __launch_bounds__(768, 3) void rnn_layer(
    const unsigned short* __restrict__ Whb,   // layer slice [3072][1024] bf16
    const unsigned short* __restrict__ xp,    // [128][128][3072] bf16
    const float* __restrict__ h0,             // [128][1024] fp32
    const float* __restrict__ bh,             // [3][1024] fp32
    unsigned short* __restrict__ hb0,
    unsigned short* __restrict__ hb1,
    unsigned short* __restrict__ seqout,      // layer0 out: bf16 [(b*128+t)*1024+o]
    float* __restrict__ lastlayer,            // layer1 out: fp32
    float* __restrict__ laststep,             // fp32 [b*1024+o]
    unsigned* __restrict__ flags,             // [8 groups][128] u32
    unsigned sbase,
    int is_last)
{
    __shared__ unsigned short As[128 * 136];  // 34816 B
    __shared__ float Cg[6528];                // 26112 B: [3g][2os][16b:68][16oi x 4kh]

    const int bid = blockIdx.x;
    const int bt = bid & 7, ot = bid >> 3;
    const int tid = threadIdx.x;
    const int lane = tid & 63, wv = tid >> 6;
    const int g = wv >> 2, kh = wv & 3;
    const int q = lane >> 4, mm = lane & 15;

    unsigned* const fgrp = flags + (bt << 7);          // 128 u32 for this group
    const unsigned* const fp0 = fgrp + lane;
    const unsigned* const fp1 = fgrp + 64 + lane;

    // ---- Wh fragments into registers (once) ----
    short8 wh0[8], wh1[8];
    {
        const unsigned short* p0 = &Whb[((g << 10) + (ot << 5) + mm) * HSZ + (kh << 8) + (q << 3)];
        const unsigned short* p1 = p0 + (HSZ << 4);
#pragma unroll
        for (int s = 0; s < 8; s++) {
            wh0[s] = *(const short8*)(p0 + (s << 5));
            wh1[s] = *(const short8*)(p1 + (s << 5));
        }
    }

    // ---- elementwise ownership: tid<256 owns (b_l, o_l, o_l+1) ----
    float hc0 = 0.f, hc1 = 0.f;
    float bh00 = 0.f, bh01 = 0.f, bh10 = 0.f, bh11 = 0.f, bh20 = 0.f, bh21 = 0.f;
    int b_g = 0, o_g = 0, b_l = 0, o_l = 0;
    unsigned xq0 = 0, xq1 = 0, xq2 = 0;       // prefetched xp (current step)
    if (tid < 256) {
        b_l = tid >> 4; o_l = (tid & 15) << 1;
        b_g = (bt << 4) + b_l;
        o_g = (ot << 5) + o_l;
        float2 v = *(const float2*)&h0[(b_g << 10) + o_g];
        hc0 = v.x; hc1 = v.y;
        bh00 = bh[o_g];        bh01 = bh[o_g + 1];
        bh10 = bh[1024 + o_g]; bh11 = bh[1024 + o_g + 1];
        bh20 = bh[2048 + o_g]; bh21 = bh[2048 + o_g + 1];
        const unsigned short* x0p = xp + b_g * R3H + o_g;
        xq0 = *(const unsigned*)(x0p);
        xq1 = *(const unsigned*)(x0p + 1024);
        xq2 = *(const unsigned*)(x0p + 2048);
        unsigned pk = (unsigned)f2b(v.x) | ((unsigned)f2b(v.y) << 16);
        __hip_atomic_store((unsigned*)&hb0[(b_g << 10) + o_g], pk,
                           __ATOMIC_RELAXED, __HIP_MEMORY_SCOPE_AGENT);
        asm volatile("s_waitcnt vmcnt(0)" ::: "memory");
        if (lane == 0)
            __hip_atomic_store(&fgrp[(ot << 2) + wv], sbase,
                               __ATOMIC_RELAXED, __HIP_MEMORY_SCOPE_AGENT);
    }

    // staging constants (waves 4..11)
    const int stid = tid - 256;
    const int sb = stid & 15, kcg = (stid >> 4) & 31;

    for (int t = 0; t < TSZ; t++) {
        const unsigned short* hr = (t & 1) ? hb1 : hb0;
        unsigned short* hw = (t & 1) ? hb0 : hb1;

        // ---- wave 4: pipelined group-local wait (3 probe slots in flight) ----
        if (wv == 4) {
            const unsigned tgt = sbase + (unsigned)t;
            unsigned a0, b0, a1, b1, a2, b2;
#define PROBE(A, B) asm volatile( \
    "global_load_dword %0, %2, off sc0 sc1\n\t" \
    "global_load_dword %1, %3, off sc0 sc1" \
    : "=v"(A), "=v"(B) : "v"(fp0), "v"(fp1) : "memory")
            PROBE(a0, b0); PROBE(a1, b1); PROBE(a2, b2);
            for (;;) {
                asm volatile("s_waitcnt vmcnt(4)" ::: "memory");
                __builtin_amdgcn_sched_barrier(0);
                if (__all(a0 >= tgt && b0 >= tgt)) break;
                PROBE(a0, b0);
                asm volatile("s_waitcnt vmcnt(4)" ::: "memory");
                __builtin_amdgcn_sched_barrier(0);
                if (__all(a1 >= tgt && b1 >= tgt)) break;
                PROBE(a1, b1);
                asm volatile("s_waitcnt vmcnt(4)" ::: "memory");
                __builtin_amdgcn_sched_barrier(0);
                if (__all(a2 >= tgt && b2 >= tgt)) break;
                PROBE(a2, b2);
            }
#undef PROBE
            asm volatile("s_waitcnt vmcnt(0)" ::: "memory");
        }
        __syncthreads();

        // ---- waves 4..11: stage h slab via L3 loads ----
        if (wv >= 4) {
            const unsigned short* src = hr + (((bt << 4) + sb) << 10) + (kcg << 3);
            u32x4 hv[4];
#pragma unroll
            for (int i = 0; i < 4; i++)
                asm volatile("global_load_dwordx4 %0, %1, off sc0 sc1"
                             : "=v"(hv[i]) : "v"(src + (i << 8)));
            asm volatile("s_waitcnt vmcnt(0)" ::: "memory");
#pragma unroll
            for (int i = 0; i < 4; i++)
                *(u32x4*)&As[(kcg + (i << 5)) * 136 + sb * 8] = hv[i];
        }
        __syncthreads();

        // ---- k-loop: pure LDS + MFMA (Wh in registers) ----
        f32x4 acc0 = (f32x4){0.f, 0.f, 0.f, 0.f};
        f32x4 acc1 = (f32x4){0.f, 0.f, 0.f, 0.f};
        {
            const unsigned short* ab = &As[((kh << 5) + q) * 136 + mm * 8];
#pragma unroll
            for (int s = 0; s < 8; s++) {
                short8 a = *(const short8*)(ab + s * 544);
                acc0 = __builtin_amdgcn_mfma_f32_16x16x32_bf16(a, wh0[s], acc0, 0, 0, 0);
                acc1 = __builtin_amdgcn_mfma_f32_16x16x32_bf16(a, wh1[s], acc1, 0, 0, 0);
            }
        }

        // ---- write f32 partials: Cg[g][os][b=4q+r : 68][oi=mm : 4][kh] ----
        {
            float* cgw = &Cg[(g << 1) * 1088 + (q << 2) * 68 + (mm << 2) + kh];
#pragma unroll
            for (int r = 0; r < 4; r++) {
                cgw[r * 68]        = acc0[r];
                cgw[1088 + r * 68] = acc1[r];
            }
        }
        __syncthreads();

        // ---- elementwise: combine partials (f32x4 per gate/o), gates, h ----
        if (tid < 256) {
            const int os = o_l >> 4, oi = o_l & 15;
            const float* cb = &Cg[os * 1088 + b_l * 68 + (oi << 2)];
            f32x4 v0a = *(const f32x4*)(cb);
            f32x4 v0b = *(const f32x4*)(cb + 4);
            f32x4 v1a = *(const f32x4*)(cb + 2176);
            f32x4 v1b = *(const f32x4*)(cb + 2180);
            f32x4 v2a = *(const f32x4*)(cb + 4352);
            f32x4 v2b = *(const f32x4*)(cb + 4356);
            const float c0a = v0a[0] + v0a[1] + v0a[2] + v0a[3];
            const float c0b = v0b[0] + v0b[1] + v0b[2] + v0b[3];
            const float c1a = v1a[0] + v1a[1] + v1a[2] + v1a[3];
            const float c1b = v1b[0] + v1b[1] + v1b[2] + v1b[3];
            const float c2a = v2a[0] + v2a[1] + v2a[2] + v2a[3];
            const float c2b = v2b[0] + v2b[1] + v2b[2] + v2b[3];
            float res0, res1;
            {
                const float x0 = bf2f((unsigned short)(xq0 & 0xffff));
                const float x1 = bf2f((unsigned short)(xq1 & 0xffff));
                const float x2 = bf2f((unsigned short)(xq2 & 0xffff));
                const float r_ = 1.f / (1.f + __expf(-(x0 + c0a + bh00)));
                const float z_ = 1.f / (1.f + __expf(-(x1 + c1a + bh10)));
                const float nn = x2 + r_ * (c2a + bh20);
                const float th = 1.f - 2.f / (__expf(2.f * nn) + 1.f);
                res0 = (1.f - z_) * th + z_ * hc0;
            }
            {
                const float x0 = bf2f((unsigned short)(xq0 >> 16));
                const float x1 = bf2f((unsigned short)(xq1 >> 16));
                const float x2 = bf2f((unsigned short)(xq2 >> 16));
                const float r_ = 1.f / (1.f + __expf(-(x0 + c0b + bh01)));
                const float z_ = 1.f / (1.f + __expf(-(x1 + c1b + bh11)));
                const float nn = x2 + r_ * (c2b + bh21);
                const float th = 1.f - 2.f / (__expf(2.f * nn) + 1.f);
                res1 = (1.f - z_) * th + z_ * hc1;
            }
            hc0 = res0; hc1 = res1;
            const unsigned pk = (unsigned)f2b(res0) | ((unsigned)f2b(res1) << 16);
            __hip_atomic_store((unsigned*)&hw[(b_g << 10) + o_g], pk,
                               __ATOMIC_RELAXED, __HIP_MEMORY_SCOPE_AGENT);
            asm volatile("s_waitcnt vmcnt(0)" ::: "memory");
            if (lane == 0)
                __hip_atomic_store(&fgrp[(ot << 2) + wv], sbase + (unsigned)t + 1u,
                                   __ATOMIC_RELAXED, __HIP_MEMORY_SCOPE_AGENT);
            // ---- off the inter-step chain: outputs + next-step xp prefetch ----
            if (!is_last) {
                *(unsigned*)&seqout[(b_g * TSZ + t) * HSZ + o_g] = pk;
            } else {
                float2 fv2; fv2.x = res0; fv2.y = res1;
                *(float2*)&lastlayer[((b_g * TSZ + t) << 10) + o_g] = fv2;
            }
            if (t == TSZ - 1) {
                float2 fv2; fv2.x = res0; fv2.y = res1;
                *(float2*)&laststep[(b_g << 10) + o_g] = fv2;
            }
            if (t + 1 < TSZ) {
                const unsigned short* xnp = xp + (t + 1) * (BSZ * R3H) + b_g * R3H + o_g;
                xq0 = *(const unsigned*)(xnp);
                xq1 = *(const unsigned*)(xnp + 1024);
                xq2 = *(const unsigned*)(xnp + 2048);
            }
        }
    }
}

// ---------------------------------------------------------------------------
// Host orchestration. ws layout (bytes) -- identical to the proven R6 build:
//   Wxb 0..12582912 | Whb ..25165824 | inb ..58720256 | h1seq ..92274688 |
//   xp ..192937984 | hb0 ..193200128 | hb1 ..193462272 | flags(4KB u32)
// Flag counters continue across layers: layer0 sbase=1 (ends 129), layer1
// sbase=130 (ends 258) -> single memset serves both.
// ---------------------------------------------------------------------------
extern "C" void kernel_launch(void* const* d_in, const int* in_sizes, int n_in,
                              void* d_out, int out_size, void* d_ws, size_t ws_size,
                              hipStream_t stream)
{
    const float* input = (const float*)d_in[0];
    const float* prevh = (const float*)d_in[1];
    const float* Wx    = (const float*)d_in[2];
    const float* Wh    = (const float*)d_in[3];
    const float* bx    = (const float*)d_in[4];
    const float* bh    = (const float*)d_in[5];
    float* out = (float*)d_out;

    char* ws = (char*)d_ws;
    unsigned short* Wxb = (unsigned short*)(ws);
    unsigned short* Whb = (unsigned short*)(ws + 12582912);
    unsigned short* inb = (unsigned short*)(ws + 25165824);
    unsigned short* h1s = (unsigned short*)(ws + 58720256);
    unsigned short* xp  = (unsigned short*)(ws + 92274688);
    unsigned short* hb0 = (unsigned short*)(ws + 192937984);
    unsigned short* hb1 = (unsigned short*)(ws + 193200128);
    unsigned*       flg = (unsigned*)(ws + 193462272);

    (void)hipMemsetAsync(flg, 0, 4096, stream);

    cvt_bf16<<<2048, 256, 0, stream>>>(input, inb, BTH / 4);
    cvt_bf16<<<1024, 256, 0, stream>>>(Wx, Wxb, 6291456 / 4);
    cvt_bf16<<<1024, 256, 0, stream>>>(Wh, Whb, 6291456 / 4);

    // ---- layer 0 ----
    gemm_xp<<<dim3(128, 24), 256, 0, stream>>>(inb, Wxb, bx, xp);
    {
        const unsigned short* a0 = Whb;
        const unsigned short* a1 = xp;
        const float* a2 = prevh;
        const float* a3 = bh;
        unsigned short* a4 = hb0;
        unsigned short* a5 = hb1;
        unsigned short* a6 = h1s;
        float* a7 = out;
        float* a8 = out + BTH;            // last_step layer 0
        unsigned* a9 = flg;
        unsigned a10 = 1u;
        int a11 = 0;
        void* args[] = {&a0, &a1, &a2, &a3, &a4, &a5, &a6, &a7, &a8, &a9, &a10, &a11};
        (void)hipLaunchCooperativeKernel((const void*)rnn_layer, dim3(NWG), dim3(768),
                                         args, 0, stream);
    }
    // ---- layer 1 ----
    gemm_xp<<<dim3(128, 24), 256, 0, stream>>>(h1s, Wxb + 3145728, bx + R3H, xp);
    {
        const unsigned short* a0 = Whb + 3145728;
        const unsigned short* a1 = xp;
        const float* a2 = prevh + BH;
        const float* a3 = bh + R3H;
        unsigned short* a4 = hb0;
        unsigned short* a5 = hb1;
        unsigned short* a6 = h1s;
        float* a7 = out;                  // last_layer_hiddens
        float* a8 = out + BTH + BH;       // last_step layer 1
        unsigned* a9 = flg;
        unsigned a10 = 130u;
        int a11 = 1;
        void* args[] = {&a0, &a1, &a2, &a3, &a4, &a5, &a6, &a7, &a8, &a9, &a10, &a11};
        (void)hipLaunchCooperativeKernel((const void*)rnn_layer, dim3(NWG), dim3(768),
                                         args, 0, stream);
    }
}

// Round 8
// 1648.508 us; speedup vs baseline: 1.3041x; 1.3041x over previous
//
#include <hip/hip_runtime.h>

// ---------------------------------------------------------------------------
// TIRGRNN: 2-layer GRU-like RNN. B=128, T=128, H=1024, L=2.
// R12: rnn_layer restored VERBATIM from R6 (measured 601us/layer; five
// protocol experiments all regressed or hung -- protocol frozen).
// gemm_xp re-tiled for traffic: each block now covers 2 timesteps x 256
// n-rows (1024 thr, 16 waves), halving W re-reads (128->64 tC blocks) and
// A re-reads (24->12 n blocks): ~1.57GB -> ~0.79GB through L2/L3 per gemm.
// Per-wave fragment geometry identical to the proven kernel (64b x 64n,
// acc[4][4], m97 global_load_lds staging, 2 insts/thread/chunk).
// ---------------------------------------------------------------------------

typedef __attribute__((ext_vector_type(8))) short short8;   // 8 x bf16
typedef __attribute__((ext_vector_type(4))) float f32x4;
typedef __attribute__((ext_vector_type(4))) unsigned int u32x4;

#define BSZ   128
#define TSZ   128
#define HSZ   1024
#define R3H   3072
#define BTH   16777216   // B*T*H
#define BH    131072     // B*H
#define NWG   256

__device__ __forceinline__ float bf2f(unsigned short u) {
    unsigned x = ((unsigned)u) << 16;
    float f; __builtin_memcpy(&f, &x, 4); return f;
}
__device__ __forceinline__ unsigned short f2b(float f) {
    unsigned x; __builtin_memcpy(&x, &f, 4);
    x += 0x7fffu + ((x >> 16) & 1u);      // RNE
    return (unsigned short)(x >> 16);
}

// ---------------------------------------------------------------------------
// fp32 -> bf16 bulk convert
// ---------------------------------------------------------------------------
__global__ void cvt_bf16(const float* __restrict__ s, unsigned short* __restrict__ d, int n4) {
    int i = blockIdx.x * blockDim.x + threadIdx.x;
    int st = gridDim.x * blockDim.x;
    for (; i < n4; i += st) {
        float4 v = ((const float4*)s)[i];
        ushort4 o;
        o.x = f2b(v.x); o.y = f2b(v.y); o.z = f2b(v.z); o.w = f2b(v.w);
        ((ushort4*)d)[i] = o;
    }
}

// ---------------------------------------------------------------------------
// async 16B/lane global->LDS. LDS dest = wave-uniform base + lane*16 (HW rule);
// global src is per-lane.
// ---------------------------------------------------------------------------
__device__ __forceinline__ void gld_lds16(const unsigned short* g, unsigned short* ldsbase) {
    typedef const unsigned int __attribute__((address_space(1)))* gp_t;
    typedef unsigned int __attribute__((address_space(3)))* lp_t;
    __builtin_amdgcn_global_load_lds(
        (gp_t)(unsigned long long)(const void*)g,
        (lp_t)(unsigned)(unsigned long long)(void*)ldsbase,
        16, 0, 0);
}

// ---------------------------------------------------------------------------
// Bulk projection GEMM, transposed output, traffic-tiled:
// xp[t][b][row] = sum_k In[(b*T+t)*H+k] * W[row*H+k] + bias[row]
// Block: 2 timesteps (tC0, tC0+1) x 256 W-rows (n0..n0+255) x all 128 b.
// 1024 threads = 16 waves; wave (bh, th, nq) owns 64b x 64n of timestep th.
// LDS per 32-k chunk: Wt[256][32] (16KB) + It[2][128][32] (16KB).
// Staging: 2 x global_load_lds dwordx4 per thread per chunk (m97 pattern).
// ---------------------------------------------------------------------------
__global__ __launch_bounds__(1024, 4) void gemm_xp(
    const unsigned short* __restrict__ A,
    const unsigned short* __restrict__ W,
    const float* __restrict__ bias,
    unsigned short* __restrict__ xp)
{
    __shared__ unsigned short Wt[256 * 32];   // 16 KB
    __shared__ unsigned short It[2 * 128 * 32]; // 16 KB

    const int tC0 = blockIdx.x << 1;
    const int n0  = blockIdx.y << 8;
    const int tid = threadIdx.x;
    const int lane = tid & 63, wv = tid >> 6;
    const int bh = wv >> 3;            // b half (0/1)
    const int th = (wv >> 2) & 1;      // timestep within pair
    const int nq = wv & 3;             // 64-row n quarter
    const int q = lane >> 4, mm = lane & 15;

    f32x4 acc[4][4];
#pragma unroll
    for (int i = 0; i < 4; i++)
#pragma unroll
        for (int j = 0; j < 4; j++) acc[i][j] = (f32x4){0.f, 0.f, 0.f, 0.f};

    // staging maps (wave-contiguous: LDS dst = wave base + lane*16)
    const int wr = tid >> 2,  wc = tid & 3;              // W: row 0..255, 16B col
    const int ti = tid >> 9;                             // A: t sub 0/1
    const int ar = (tid >> 2) & 127, ac = tid & 3;       // A: b row, 16B col
    const unsigned short* wgp = &W[(n0 + wr) * HSZ + (wc << 3)];
    const unsigned short* agp = &A[(ar * TSZ + tC0 + ti) * HSZ + (ac << 3)];
    unsigned short* wdst = &Wt[wr * 32 + (wc << 3)];
    unsigned short* adst = &It[(ti << 12) + ar * 32 + (ac << 3)];

    for (int kk = 0; kk < 32; kk++) {
        const int kb = kk << 5;
        __syncthreads();                               // prev-iter LDS reads done
        gld_lds16(wgp + kb, wdst);
        gld_lds16(agp + kb, adst);
        asm volatile("s_waitcnt vmcnt(0)" ::: "memory");
        __syncthreads();                               // all waves' LDS writes landed
        short8 af[4], bf[4];
#pragma unroll
        for (int mi = 0; mi < 4; mi++)
            af[mi] = *(const short8*)&It[(th << 12) + (((bh << 6) + mi * 16 + mm) << 5) + (q << 3)];
#pragma unroll
        for (int ni = 0; ni < 4; ni++)
            bf[ni] = *(const short8*)&Wt[(((nq << 6) + ni * 16 + mm) << 5) + (q << 3)];
#pragma unroll
        for (int mi = 0; mi < 4; mi++)
#pragma unroll
            for (int ni = 0; ni < 4; ni++)
                acc[mi][ni] = __builtin_amdgcn_mfma_f32_16x16x32_bf16(af[mi], bf[ni], acc[mi][ni], 0, 0, 0);
    }

    // epilogue: D row (m)=b, col (n)=wrow; xp slab [b][3072] for timestep tC0+th
    unsigned short* slab = xp + (tC0 + th) * (BSZ * R3H);
#pragma unroll
    for (int ni = 0; ni < 4; ni++) {
        const int wrow = n0 + (nq << 6) + ni * 16 + mm;
        const float bs = bias[wrow];
#pragma unroll
        for (int mi = 0; mi < 4; mi++) {
            const int bb = (bh << 6) + mi * 16 + (q << 2);
#pragma unroll
            for (int r = 0; r < 4; r++)
                slab[(bb + r) * R3H + wrow] = f2b(acc[mi][ni][r] + bs);
        }
    }
}

// ---------------------------------------------------------------------------
// Persistent recurrence kernel -- VERBATIM R6 (measured 601us/layer).
// 256 wgs x 768 thr (12 waves). wg (bt,ot): b in [bt*16,+16), o in [ot*32,+32).
// 8 independent bt-group flag protocols; u32 flags, 512B/group; monotonic
// counters. Per step: wave 4 polls -> bar -> waves 4-11 stage h slab -> bar
// -> MFMA k-loop + Cg partials -> bar -> waves 0-3 gates + h store +
// own-store vmcnt + per-wave flag; outputs & xp prefetch AFTER the flag.
// ---------------------------------------------------------------------------
__global__ __launch_bounds__(768, 3) void rnn_layer(
    const unsigned short* __restrict__ Whb,   // layer slice [3072][1024] bf16
    const unsigned short* __restrict__ xp,    // [128][128][3072] bf16
    const float* __restrict__ h0,             // [128][1024] fp32
    const float* __restrict__ bh,             // [3][1024] fp32
    unsigned short* __restrict__ hb0,
    unsigned short* __restrict__ hb1,
    unsigned short* __restrict__ seqout,      // layer0 out: bf16 [(b*128+t)*1024+o]
    float* __restrict__ lastlayer,            // layer1 out: fp32
    float* __restrict__ laststep,             // fp32 [b*1024+o]
    unsigned* __restrict__ flags,             // [8 groups][128] u32
    unsigned sbase,
    int is_last)
{
    __shared__ unsigned short As[128 * 136];  // 34816 B
    __shared__ float Cg[6528];                // 26112 B: [3g][2os][4kh][16b][17]

    const int bid = blockIdx.x;
    const int bt = bid & 7, ot = bid >> 3;
    const int tid = threadIdx.x;
    const int lane = tid & 63, wv = tid >> 6;
    const int g = wv >> 2, kh = wv & 3;
    const int q = lane >> 4, mm = lane & 15;

    unsigned* const fgrp = flags + (bt << 7);          // 128 u32 for this group
    const unsigned* const fp0 = fgrp + lane;
    const unsigned* const fp1 = fgrp + 64 + lane;

    // ---- Wh fragments into registers (once) ----
    short8 wh0[8], wh1[8];
    {
        const unsigned short* p0 = &Whb[((g << 10) + (ot << 5) + mm) * HSZ + (kh << 8) + (q << 3)];
        const unsigned short* p1 = p0 + (HSZ << 4);
#pragma unroll
        for (int s = 0; s < 8; s++) {
            wh0[s] = *(const short8*)(p0 + (s << 5));
            wh1[s] = *(const short8*)(p1 + (s << 5));
        }
    }

    // ---- elementwise ownership: tid<256 owns (b_l, o_l, o_l+1) ----
    float hc0 = 0.f, hc1 = 0.f;
    float bh00 = 0.f, bh01 = 0.f, bh10 = 0.f, bh11 = 0.f, bh20 = 0.f, bh21 = 0.f;
    int b_g = 0, o_g = 0, b_l = 0, o_l = 0;
    unsigned xq0 = 0, xq1 = 0, xq2 = 0;       // prefetched xp (current step)
    if (tid < 256) {
        b_l = tid >> 4; o_l = (tid & 15) << 1;
        b_g = (bt << 4) + b_l;
        o_g = (ot << 5) + o_l;
        float2 v = *(const float2*)&h0[(b_g << 10) + o_g];
        hc0 = v.x; hc1 = v.y;
        bh00 = bh[o_g];        bh01 = bh[o_g + 1];
        bh10 = bh[1024 + o_g]; bh11 = bh[1024 + o_g + 1];
        bh20 = bh[2048 + o_g]; bh21 = bh[2048 + o_g + 1];
        const unsigned short* x0p = xp + b_g * R3H + o_g;
        xq0 = *(const unsigned*)(x0p);
        xq1 = *(const unsigned*)(x0p + 1024);
        xq2 = *(const unsigned*)(x0p + 2048);
        unsigned pk = (unsigned)f2b(v.x) | ((unsigned)f2b(v.y) << 16);
        __hip_atomic_store((unsigned*)&hb0[(b_g << 10) + o_g], pk,
                           __ATOMIC_RELAXED, __HIP_MEMORY_SCOPE_AGENT);
        asm volatile("s_waitcnt vmcnt(0)" ::: "memory");
        if (lane == 0)
            __hip_atomic_store(&fgrp[(ot << 2) + wv], sbase,
                               __ATOMIC_RELAXED, __HIP_MEMORY_SCOPE_AGENT);
    }

    // staging constants (waves 4..11)
    const int stid = tid - 256;
    const int sb = stid & 15, kcg = (stid >> 4) & 31;

    for (int t = 0; t < TSZ; t++) {
        const unsigned short* hr = (t & 1) ? hb1 : hb0;
        unsigned short* hw = (t & 1) ? hb0 : hb1;

        // ---- wave 4: group-local wait (all 128 wave-flags >= sbase+t) ----
        if (wv == 4) {
            const unsigned tgt = sbase + (unsigned)t;
            for (;;) {
                unsigned a0 = __hip_atomic_load(fp0, __ATOMIC_RELAXED, __HIP_MEMORY_SCOPE_AGENT);
                unsigned a1 = __hip_atomic_load(fp1, __ATOMIC_RELAXED, __HIP_MEMORY_SCOPE_AGENT);
                if (__all(a0 >= tgt && a1 >= tgt)) break;
                __builtin_amdgcn_s_sleep(1);
            }
        }
        __syncthreads();

        // ---- waves 4..11: stage h slab via L3 loads ----
        if (wv >= 4) {
            const unsigned short* src = hr + (((bt << 4) + sb) << 10) + (kcg << 3);
            u32x4 hv[4];
#pragma unroll
            for (int i = 0; i < 4; i++)
                asm volatile("global_load_dwordx4 %0, %1, off sc0 sc1"
                             : "=v"(hv[i]) : "v"(src + (i << 8)));
            asm volatile("s_waitcnt vmcnt(0)" ::: "memory");
#pragma unroll
            for (int i = 0; i < 4; i++)
                *(u32x4*)&As[(kcg + (i << 5)) * 136 + sb * 8] = hv[i];
        }
        __syncthreads();

        // ---- k-loop: pure LDS + MFMA (Wh in registers) ----
        f32x4 acc0 = (f32x4){0.f, 0.f, 0.f, 0.f};
        f32x4 acc1 = (f32x4){0.f, 0.f, 0.f, 0.f};
        {
            const unsigned short* ab = &As[((kh << 5) + q) * 136 + mm * 8];
#pragma unroll
            for (int s = 0; s < 8; s++) {
                short8 a = *(const short8*)(ab + s * 544);
                acc0 = __builtin_amdgcn_mfma_f32_16x16x32_bf16(a, wh0[s], acc0, 0, 0, 0);
                acc1 = __builtin_amdgcn_mfma_f32_16x16x32_bf16(a, wh1[s], acc1, 0, 0, 0);
            }
        }

        // ---- write f32 partials ----
        {
            float* cgw = &Cg[((g << 3) + kh) * 272 + (q << 2) * 17 + mm];
#pragma unroll
            for (int r = 0; r < 4; r++) {
                cgw[r * 17]        = acc0[r];
                cgw[1088 + r * 17] = acc1[r];
            }
        }
        __syncthreads();

        // ---- elementwise: combine partials, gates, h update ----
        if (tid < 256) {
            const int os = o_l >> 4, ol2 = o_l & 15;
            const float* cb = &Cg[os * 1088 + b_l * 17 + ol2];
            float c0a, c0b, c1a, c1b, c2a, c2b;
            {
                const float* p = cb;
                c0a = p[0] + p[272] + p[544] + p[816];
                c0b = p[1] + p[273] + p[545] + p[817];
                p = cb + 2176;
                c1a = p[0] + p[272] + p[544] + p[816];
                c1b = p[1] + p[273] + p[545] + p[817];
                p = cb + 4352;
                c2a = p[0] + p[272] + p[544] + p[816];
                c2b = p[1] + p[273] + p[545] + p[817];
            }
            float res0, res1;
            {
                const float x0 = bf2f((unsigned short)(xq0 & 0xffff));
                const float x1 = bf2f((unsigned short)(xq1 & 0xffff));
                const float x2 = bf2f((unsigned short)(xq2 & 0xffff));
                const float r_ = 1.f / (1.f + __expf(-(x0 + c0a + bh00)));
                const float z_ = 1.f / (1.f + __expf(-(x1 + c1a + bh10)));
                const float nn = x2 + r_ * (c2a + bh20);
                const float th = 1.f - 2.f / (__expf(2.f * nn) + 1.f);
                res0 = (1.f - z_) * th + z_ * hc0;
            }
            {
                const float x0 = bf2f((unsigned short)(xq0 >> 16));
                const float x1 = bf2f((unsigned short)(xq1 >> 16));
                const float x2 = bf2f((unsigned short)(xq2 >> 16));
                const float r_ = 1.f / (1.f + __expf(-(x0 + c0b + bh01)));
                const float z_ = 1.f / (1.f + __expf(-(x1 + c1b + bh11)));
                const float nn = x2 + r_ * (c2b + bh21);
                const float th = 1.f - 2.f / (__expf(2.f * nn) + 1.f);
                res1 = (1.f - z_) * th + z_ * hc1;
            }
            hc0 = res0; hc1 = res1;
            const unsigned pk = (unsigned)f2b(res0) | ((unsigned)f2b(res1) << 16);
            __hip_atomic_store((unsigned*)&hw[(b_g << 10) + o_g], pk,
                               __ATOMIC_RELAXED, __HIP_MEMORY_SCOPE_AGENT);
            asm volatile("s_waitcnt vmcnt(0)" ::: "memory");
            if (lane == 0)
                __hip_atomic_store(&fgrp[(ot << 2) + wv], sbase + (unsigned)t + 1u,
                                   __ATOMIC_RELAXED, __HIP_MEMORY_SCOPE_AGENT);
            // ---- off the inter-step chain: outputs + next-step xp prefetch ----
            if (!is_last) {
                *(unsigned*)&seqout[(b_g * TSZ + t) * HSZ + o_g] = pk;
            } else {
                float2 fv2; fv2.x = res0; fv2.y = res1;
                *(float2*)&lastlayer[((b_g * TSZ + t) << 10) + o_g] = fv2;
            }
            if (t == TSZ - 1) {
                float2 fv2; fv2.x = res0; fv2.y = res1;
                *(float2*)&laststep[(b_g << 10) + o_g] = fv2;
            }
            if (t + 1 < TSZ) {
                const unsigned short* xnp = xp + (t + 1) * (BSZ * R3H) + b_g * R3H + o_g;
                xq0 = *(const unsigned*)(xnp);
                xq1 = *(const unsigned*)(xnp + 1024);
                xq2 = *(const unsigned*)(xnp + 2048);
            }
        }
    }
}

// ---------------------------------------------------------------------------
// Host orchestration. ws layout (bytes) -- identical to the proven R6 build:
//   Wxb 0..12582912 | Whb ..25165824 | inb ..58720256 | h1seq ..92274688 |
//   xp ..192937984 | hb0 ..193200128 | hb1 ..193462272 | flags(4KB u32)
// Flag counters continue across layers: layer0 sbase=1 (ends 129), layer1
// sbase=130 (ends 258) -> single memset serves both.
// ---------------------------------------------------------------------------
extern "C" void kernel_launch(void* const* d_in, const int* in_sizes, int n_in,
                              void* d_out, int out_size, void* d_ws, size_t ws_size,
                              hipStream_t stream)
{
    const float* input = (const float*)d_in[0];
    const float* prevh = (const float*)d_in[1];
    const float* Wx    = (const float*)d_in[2];
    const float* Wh    = (const float*)d_in[3];
    const float* bx    = (const float*)d_in[4];
    const float* bh    = (const float*)d_in[5];
    float* out = (float*)d_out;

    char* ws = (char*)d_ws;
    unsigned short* Wxb = (unsigned short*)(ws);
    unsigned short* Whb = (unsigned short*)(ws + 12582912);
    unsigned short* inb = (unsigned short*)(ws + 25165824);
    unsigned short* h1s = (unsigned short*)(ws + 58720256);
    unsigned short* xp  = (unsigned short*)(ws + 92274688);
    unsigned short* hb0 = (unsigned short*)(ws + 192937984);
    unsigned short* hb1 = (unsigned short*)(ws + 193200128);
    unsigned*       flg = (unsigned*)(ws + 193462272);

    (void)hipMemsetAsync(flg, 0, 4096, stream);

    cvt_bf16<<<2048, 256, 0, stream>>>(input, inb, BTH / 4);
    cvt_bf16<<<1024, 256, 0, stream>>>(Wx, Wxb, 6291456 / 4);
    cvt_bf16<<<1024, 256, 0, stream>>>(Wh, Whb, 6291456 / 4);

    // ---- layer 0 ----
    gemm_xp<<<dim3(64, 12), 1024, 0, stream>>>(inb, Wxb, bx, xp);
    {
        const unsigned short* a0 = Whb;
        const unsigned short* a1 = xp;
        const float* a2 = prevh;
        const float* a3 = bh;
        unsigned short* a4 = hb0;
        unsigned short* a5 = hb1;
        unsigned short* a6 = h1s;
        float* a7 = out;
        float* a8 = out + BTH;            // last_step layer 0
        unsigned* a9 = flg;
        unsigned a10 = 1u;
        int a11 = 0;
        void* args[] = {&a0, &a1, &a2, &a3, &a4, &a5, &a6, &a7, &a8, &a9, &a10, &a11};
        (void)hipLaunchCooperativeKernel((const void*)rnn_layer, dim3(NWG), dim3(768),
                                         args, 0, stream);
    }
    // ---- layer 1 ----
    gemm_xp<<<dim3(64, 12), 1024, 0, stream>>>(h1s, Wxb + 3145728, bx + R3H, xp);
    {
        const unsigned short* a0 = Whb + 3145728;
        const unsigned short* a1 = xp;
        const float* a2 = prevh + BH;
        const float* a3 = bh + R3H;
        unsigned short* a4 = hb0;
        unsigned short* a5 = hb1;
        unsigned short* a6 = h1s;
        float* a7 = out;                  // last_layer_hiddens
        float* a8 = out + BTH + BH;       // last_step layer 1
        unsigned* a9 = flg;
        unsigned a10 = 130u;
        int a11 = 1;
        void* args[] = {&a0, &a1, &a2, &a3, &a4, &a5, &a6, &a7, &a8, &a9, &a10, &a11};
        (void)hipLaunchCooperativeKernel((const void*)rnn_layer, dim3(NWG), dim3(768),
                                         args, 0, stream);
    }
}

// Round 10
// 1581.073 us; speedup vs baseline: 1.3598x; 1.0427x over previous
//
#include <hip/hip_runtime.h>

// ---------------------------------------------------------------------------
// TIRGRNN: 2-layer GRU-like RNN. B=128, T=128, H=1024, L=2.
// R14 = R13 resubmitted verbatim (R13's run died on container acquisition,
// not a kernel fault). Single delta vs the proven R12 build: gemm_xp grid
// swapped to x=n(24), y=tC(128). With 24 % 8 == 0, round-robin XCD dispatch
// pins each XCD to the same 3 W-tiles (768KB, L2-resident) and the 3
// co-resident blocks per XCD per tC-window share one A-tile: L3 traffic
// ~780MB -> ~262MB per gemm. Kernel bodies byte-identical to proven code;
// rnn_layer verbatim R6 (measured 591-601us/layer).
// ---------------------------------------------------------------------------

typedef __attribute__((ext_vector_type(8))) short short8;   // 8 x bf16
typedef __attribute__((ext_vector_type(4))) float f32x4;
typedef __attribute__((ext_vector_type(4))) unsigned int u32x4;

#define BSZ   128
#define TSZ   128
#define HSZ   1024
#define R3H   3072
#define BTH   16777216   // B*T*H
#define BH    131072     // B*H
#define NWG   256

__device__ __forceinline__ float bf2f(unsigned short u) {
    unsigned x = ((unsigned)u) << 16;
    float f; __builtin_memcpy(&f, &x, 4); return f;
}
__device__ __forceinline__ unsigned short f2b(float f) {
    unsigned x; __builtin_memcpy(&x, &f, 4);
    x += 0x7fffu + ((x >> 16) & 1u);      // RNE
    return (unsigned short)(x >> 16);
}

// ---------------------------------------------------------------------------
// fp32 -> bf16 bulk convert
// ---------------------------------------------------------------------------
__global__ void cvt_bf16(const float* __restrict__ s, unsigned short* __restrict__ d, int n4) {
    int i = blockIdx.x * blockDim.x + threadIdx.x;
    int st = gridDim.x * blockDim.x;
    for (; i < n4; i += st) {
        float4 v = ((const float4*)s)[i];
        ushort4 o;
        o.x = f2b(v.x); o.y = f2b(v.y); o.z = f2b(v.z); o.w = f2b(v.w);
        ((ushort4*)d)[i] = o;
    }
}

// ---------------------------------------------------------------------------
// async 16B/lane global->LDS. LDS dest = wave-uniform base + lane*16 (HW rule);
// global src is per-lane.
// ---------------------------------------------------------------------------
__device__ __forceinline__ void gld_lds16(const unsigned short* g, unsigned short* ldsbase) {
    typedef const unsigned int __attribute__((address_space(1)))* gp_t;
    typedef unsigned int __attribute__((address_space(3)))* lp_t;
    __builtin_amdgcn_global_load_lds(
        (gp_t)(unsigned long long)(const void*)g,
        (lp_t)(unsigned)(unsigned long long)(void*)ldsbase,
        16, 0, 0);
}

// ---------------------------------------------------------------------------
// Bulk projection GEMM, transposed output:
// xp[t][b][row] = sum_k In[(b*T+t)*H+k] * W[row*H+k] + bias[row]
// m97-style staging: linear LDS [row][32 shorts], global_load_lds dwordx4.
// Grid: x = n-tile (24), y = tC (128)  [swapped for XCD-pinned W reuse]
// ---------------------------------------------------------------------------
__global__ __launch_bounds__(256) void gemm_xp(
    const unsigned short* __restrict__ A,
    const unsigned short* __restrict__ W,
    const float* __restrict__ bias,
    unsigned short* __restrict__ xp)
{
    __shared__ unsigned short Wt[128 * 32];
    __shared__ unsigned short It[128 * 32];

    const int tC  = blockIdx.y;
    const int n0  = blockIdx.x << 7;
    const int tid = threadIdx.x;
    const int lane = tid & 63, wv = tid >> 6;
    const int mh = (wv >> 1) << 6;     // b half
    const int nh = (wv & 1) << 6;      // wrow half
    const int q = lane >> 4, mm = lane & 15;

    f32x4 acc[4][4];
#pragma unroll
    for (int i = 0; i < 4; i++)
#pragma unroll
        for (int j = 0; j < 4; j++) acc[i][j] = (f32x4){0.f, 0.f, 0.f, 0.f};

    const int r_l = (wv << 5) + (lane >> 2);
    const int c8  = (lane & 3) << 3;                  // short offset in 32-short row
    const unsigned short* ag0 = &A[(r_l * TSZ + tC) * HSZ + c8];
    const unsigned short* ag1 = &A[((r_l + 16) * TSZ + tC) * HSZ + c8];
    const unsigned short* wg0 = &W[(n0 + r_l) * HSZ + c8];
    const unsigned short* wg1 = &W[(n0 + r_l + 16) * HSZ + c8];
    unsigned short* itb0 = &It[(wv << 10)];           // (wv*32 rows)*32 shorts
    unsigned short* itb1 = &It[(wv << 10) + 512];     // +16 rows
    unsigned short* wtb0 = &Wt[(wv << 10)];
    unsigned short* wtb1 = &Wt[(wv << 10) + 512];

    for (int kk = 0; kk < 32; kk++) {
        const int kb = kk << 5;
        __syncthreads();                               // prev-iter LDS reads done
        gld_lds16(ag0 + kb, itb0);
        gld_lds16(ag1 + kb, itb1);
        gld_lds16(wg0 + kb, wtb0);
        gld_lds16(wg1 + kb, wtb1);
        asm volatile("s_waitcnt vmcnt(0)" ::: "memory");
        __syncthreads();                               // all waves' LDS writes landed
        short8 af[4], bf[4];
#pragma unroll
        for (int mi = 0; mi < 4; mi++)
            af[mi] = *(const short8*)&It[((mh + mi * 16 + mm) << 5) + (q << 3)];
#pragma unroll
        for (int ni = 0; ni < 4; ni++)
            bf[ni] = *(const short8*)&Wt[((nh + ni * 16 + mm) << 5) + (q << 3)];
#pragma unroll
        for (int mi = 0; mi < 4; mi++)
#pragma unroll
            for (int ni = 0; ni < 4; ni++)
                acc[mi][ni] = __builtin_amdgcn_mfma_f32_16x16x32_bf16(af[mi], bf[ni], acc[mi][ni], 0, 0, 0);
    }

    // epilogue: D row (m)=b, col (n)=wrow; xp slab [b][3072]
    unsigned short* slab = xp + tC * (BSZ * R3H);
#pragma unroll
    for (int ni = 0; ni < 4; ni++) {
        const int wrow = n0 + nh + ni * 16 + mm;
        const float bs = bias[wrow];
#pragma unroll
        for (int mi = 0; mi < 4; mi++) {
            const int bb = mh + mi * 16 + (q << 2);
#pragma unroll
            for (int r = 0; r < 4; r++)
                slab[(bb + r) * R3H + wrow] = f2b(acc[mi][ni][r] + bs);
        }
    }
}

// ---------------------------------------------------------------------------
// Persistent recurrence kernel -- VERBATIM R6 (measured 591-601us/layer).
// 256 wgs x 768 thr (12 waves). wg (bt,ot): b in [bt*16,+16), o in [ot*32,+32).
// 8 independent bt-group flag protocols; u32 flags, 512B/group; monotonic
// counters. Per step: wave 4 polls -> bar -> waves 4-11 stage h slab -> bar
// -> MFMA k-loop + Cg partials -> bar -> waves 0-3 gates + h store +
// own-store vmcnt + per-wave flag; outputs & xp prefetch AFTER the flag.
// ---------------------------------------------------------------------------
__global__ __launch_bounds__(768, 3) void rnn_layer(
    const unsigned short* __restrict__ Whb,   // layer slice [3072][1024] bf16
    const unsigned short* __restrict__ xp,    // [128][128][3072] bf16
    const float* __restrict__ h0,             // [128][1024] fp32
    const float* __restrict__ bh,             // [3][1024] fp32
    unsigned short* __restrict__ hb0,
    unsigned short* __restrict__ hb1,
    unsigned short* __restrict__ seqout,      // layer0 out: bf16 [(b*128+t)*1024+o]
    float* __restrict__ lastlayer,            // layer1 out: fp32
    float* __restrict__ laststep,             // fp32 [b*1024+o]
    unsigned* __restrict__ flags,             // [8 groups][128] u32
    unsigned sbase,
    int is_last)
{
    __shared__ unsigned short As[128 * 136];  // 34816 B
    __shared__ float Cg[6528];                // 26112 B: [3g][2os][4kh][16b][17]

    const int bid = blockIdx.x;
    const int bt = bid & 7, ot = bid >> 3;
    const int tid = threadIdx.x;
    const int lane = tid & 63, wv = tid >> 6;
    const int g = wv >> 2, kh = wv & 3;
    const int q = lane >> 4, mm = lane & 15;

    unsigned* const fgrp = flags + (bt << 7);          // 128 u32 for this group
    const unsigned* const fp0 = fgrp + lane;
    const unsigned* const fp1 = fgrp + 64 + lane;

    // ---- Wh fragments into registers (once) ----
    short8 wh0[8], wh1[8];
    {
        const unsigned short* p0 = &Whb[((g << 10) + (ot << 5) + mm) * HSZ + (kh << 8) + (q << 3)];
        const unsigned short* p1 = p0 + (HSZ << 4);
#pragma unroll
        for (int s = 0; s < 8; s++) {
            wh0[s] = *(const short8*)(p0 + (s << 5));
            wh1[s] = *(const short8*)(p1 + (s << 5));
        }
    }

    // ---- elementwise ownership: tid<256 owns (b_l, o_l, o_l+1) ----
    float hc0 = 0.f, hc1 = 0.f;
    float bh00 = 0.f, bh01 = 0.f, bh10 = 0.f, bh11 = 0.f, bh20 = 0.f, bh21 = 0.f;
    int b_g = 0, o_g = 0, b_l = 0, o_l = 0;
    unsigned xq0 = 0, xq1 = 0, xq2 = 0;       // prefetched xp (current step)
    if (tid < 256) {
        b_l = tid >> 4; o_l = (tid & 15) << 1;
        b_g = (bt << 4) + b_l;
        o_g = (ot << 5) + o_l;
        float2 v = *(const float2*)&h0[(b_g << 10) + o_g];
        hc0 = v.x; hc1 = v.y;
        bh00 = bh[o_g];        bh01 = bh[o_g + 1];
        bh10 = bh[1024 + o_g]; bh11 = bh[1024 + o_g + 1];
        bh20 = bh[2048 + o_g]; bh21 = bh[2048 + o_g + 1];
        const unsigned short* x0p = xp + b_g * R3H + o_g;
        xq0 = *(const unsigned*)(x0p);
        xq1 = *(const unsigned*)(x0p + 1024);
        xq2 = *(const unsigned*)(x0p + 2048);
        unsigned pk = (unsigned)f2b(v.x) | ((unsigned)f2b(v.y) << 16);
        __hip_atomic_store((unsigned*)&hb0[(b_g << 10) + o_g], pk,
                           __ATOMIC_RELAXED, __HIP_MEMORY_SCOPE_AGENT);
        asm volatile("s_waitcnt vmcnt(0)" ::: "memory");
        if (lane == 0)
            __hip_atomic_store(&fgrp[(ot << 2) + wv], sbase,
                               __ATOMIC_RELAXED, __HIP_MEMORY_SCOPE_AGENT);
    }

    // staging constants (waves 4..11)
    const int stid = tid - 256;
    const int sb = stid & 15, kcg = (stid >> 4) & 31;

    for (int t = 0; t < TSZ; t++) {
        const unsigned short* hr = (t & 1) ? hb1 : hb0;
        unsigned short* hw = (t & 1) ? hb0 : hb1;

        // ---- wave 4: group-local wait (all 128 wave-flags >= sbase+t) ----
        if (wv == 4) {
            const unsigned tgt = sbase + (unsigned)t;
            for (;;) {
                unsigned a0 = __hip_atomic_load(fp0, __ATOMIC_RELAXED, __HIP_MEMORY_SCOPE_AGENT);
                unsigned a1 = __hip_atomic_load(fp1, __ATOMIC_RELAXED, __HIP_MEMORY_SCOPE_AGENT);
                if (__all(a0 >= tgt && a1 >= tgt)) break;
                __builtin_amdgcn_s_sleep(1);
            }
        }
        __syncthreads();

        // ---- waves 4..11: stage h slab via L3 loads ----
        if (wv >= 4) {
            const unsigned short* src = hr + (((bt << 4) + sb) << 10) + (kcg << 3);
            u32x4 hv[4];
#pragma unroll
            for (int i = 0; i < 4; i++)
                asm volatile("global_load_dwordx4 %0, %1, off sc0 sc1"
                             : "=v"(hv[i]) : "v"(src + (i << 8)));
            asm volatile("s_waitcnt vmcnt(0)" ::: "memory");
#pragma unroll
            for (int i = 0; i < 4; i++)
                *(u32x4*)&As[(kcg + (i << 5)) * 136 + sb * 8] = hv[i];
        }
        __syncthreads();

        // ---- k-loop: pure LDS + MFMA (Wh in registers) ----
        f32x4 acc0 = (f32x4){0.f, 0.f, 0.f, 0.f};
        f32x4 acc1 = (f32x4){0.f, 0.f, 0.f, 0.f};
        {
            const unsigned short* ab = &As[((kh << 5) + q) * 136 + mm * 8];
#pragma unroll
            for (int s = 0; s < 8; s++) {
                short8 a = *(const short8*)(ab + s * 544);
                acc0 = __builtin_amdgcn_mfma_f32_16x16x32_bf16(a, wh0[s], acc0, 0, 0, 0);
                acc1 = __builtin_amdgcn_mfma_f32_16x16x32_bf16(a, wh1[s], acc1, 0, 0, 0);
            }
        }

        // ---- write f32 partials ----
        {
            float* cgw = &Cg[((g << 3) + kh) * 272 + (q << 2) * 17 + mm];
#pragma unroll
            for (int r = 0; r < 4; r++) {
                cgw[r * 17]        = acc0[r];
                cgw[1088 + r * 17] = acc1[r];
            }
        }
        __syncthreads();

        // ---- elementwise: combine partials, gates, h update ----
        if (tid < 256) {
            const int os = o_l >> 4, ol2 = o_l & 15;
            const float* cb = &Cg[os * 1088 + b_l * 17 + ol2];
            float c0a, c0b, c1a, c1b, c2a, c2b;
            {
                const float* p = cb;
                c0a = p[0] + p[272] + p[544] + p[816];
                c0b = p[1] + p[273] + p[545] + p[817];
                p = cb + 2176;
                c1a = p[0] + p[272] + p[544] + p[816];
                c1b = p[1] + p[273] + p[545] + p[817];
                p = cb + 4352;
                c2a = p[0] + p[272] + p[544] + p[816];
                c2b = p[1] + p[273] + p[545] + p[817];
            }
            float res0, res1;
            {
                const float x0 = bf2f((unsigned short)(xq0 & 0xffff));
                const float x1 = bf2f((unsigned short)(xq1 & 0xffff));
                const float x2 = bf2f((unsigned short)(xq2 & 0xffff));
                const float r_ = 1.f / (1.f + __expf(-(x0 + c0a + bh00)));
                const float z_ = 1.f / (1.f + __expf(-(x1 + c1a + bh10)));
                const float nn = x2 + r_ * (c2a + bh20);
                const float th = 1.f - 2.f / (__expf(2.f * nn) + 1.f);
                res0 = (1.f - z_) * th + z_ * hc0;
            }
            {
                const float x0 = bf2f((unsigned short)(xq0 >> 16));
                const float x1 = bf2f((unsigned short)(xq1 >> 16));
                const float x2 = bf2f((unsigned short)(xq2 >> 16));
                const float r_ = 1.f / (1.f + __expf(-(x0 + c0b + bh01)));
                const float z_ = 1.f / (1.f + __expf(-(x1 + c1b + bh11)));
                const float nn = x2 + r_ * (c2b + bh21);
                const float th = 1.f - 2.f / (__expf(2.f * nn) + 1.f);
                res1 = (1.f - z_) * th + z_ * hc1;
            }
            hc0 = res0; hc1 = res1;
            const unsigned pk = (unsigned)f2b(res0) | ((unsigned)f2b(res1) << 16);
            __hip_atomic_store((unsigned*)&hw[(b_g << 10) + o_g], pk,
                               __ATOMIC_RELAXED, __HIP_MEMORY_SCOPE_AGENT);
            asm volatile("s_waitcnt vmcnt(0)" ::: "memory");
            if (lane == 0)
                __hip_atomic_store(&fgrp[(ot << 2) + wv], sbase + (unsigned)t + 1u,
                                   __ATOMIC_RELAXED, __HIP_MEMORY_SCOPE_AGENT);
            // ---- off the inter-step chain: outputs + next-step xp prefetch ----
            if (!is_last) {
                *(unsigned*)&seqout[(b_g * TSZ + t) * HSZ + o_g] = pk;
            } else {
                float2 fv2; fv2.x = res0; fv2.y = res1;
                *(float2*)&lastlayer[((b_g * TSZ + t) << 10) + o_g] = fv2;
            }
            if (t == TSZ - 1) {
                float2 fv2; fv2.x = res0; fv2.y = res1;
                *(float2*)&laststep[(b_g << 10) + o_g] = fv2;
            }
            if (t + 1 < TSZ) {
                const unsigned short* xnp = xp + (t + 1) * (BSZ * R3H) + b_g * R3H + o_g;
                xq0 = *(const unsigned*)(xnp);
                xq1 = *(const unsigned*)(xnp + 1024);
                xq2 = *(const unsigned*)(xnp + 2048);
            }
        }
    }
}

// ---------------------------------------------------------------------------
// Host orchestration. ws layout (bytes) -- identical to the proven R6 build:
//   Wxb 0..12582912 | Whb ..25165824 | inb ..58720256 | h1seq ..92274688 |
//   xp ..192937984 | hb0 ..193200128 | hb1 ..193462272 | flags(4KB u32)
// Flag counters continue across layers: layer0 sbase=1 (ends 129), layer1
// sbase=130 (ends 258) -> single memset serves both.
// ---------------------------------------------------------------------------
extern "C" void kernel_launch(void* const* d_in, const int* in_sizes, int n_in,
                              void* d_out, int out_size, void* d_ws, size_t ws_size,
                              hipStream_t stream)
{
    const float* input = (const float*)d_in[0];
    const float* prevh = (const float*)d_in[1];
    const float* Wx    = (const float*)d_in[2];
    const float* Wh    = (const float*)d_in[3];
    const float* bx    = (const float*)d_in[4];
    const float* bh    = (const float*)d_in[5];
    float* out = (float*)d_out;

    char* ws = (char*)d_ws;
    unsigned short* Wxb = (unsigned short*)(ws);
    unsigned short* Whb = (unsigned short*)(ws + 12582912);
    unsigned short* inb = (unsigned short*)(ws + 25165824);
    unsigned short* h1s = (unsigned short*)(ws + 58720256);
    unsigned short* xp  = (unsigned short*)(ws + 92274688);
    unsigned short* hb0 = (unsigned short*)(ws + 192937984);
    unsigned short* hb1 = (unsigned short*)(ws + 193200128);
    unsigned*       flg = (unsigned*)(ws + 193462272);

    (void)hipMemsetAsync(flg, 0, 4096, stream);

    cvt_bf16<<<2048, 256, 0, stream>>>(input, inb, BTH / 4);
    cvt_bf16<<<1024, 256, 0, stream>>>(Wx, Wxb, 6291456 / 4);
    cvt_bf16<<<1024, 256, 0, stream>>>(Wh, Whb, 6291456 / 4);

    // ---- layer 0 ----
    gemm_xp<<<dim3(24, 128), 256, 0, stream>>>(inb, Wxb, bx, xp);
    {
        const unsigned short* a0 = Whb;
        const unsigned short* a1 = xp;
        const float* a2 = prevh;
        const float* a3 = bh;
        unsigned short* a4 = hb0;
        unsigned short* a5 = hb1;
        unsigned short* a6 = h1s;
        float* a7 = out;
        float* a8 = out + BTH;            // last_step layer 0
        unsigned* a9 = flg;
        unsigned a10 = 1u;
        int a11 = 0;
        void* args[] = {&a0, &a1, &a2, &a3, &a4, &a5, &a6, &a7, &a8, &a9, &a10, &a11};
        (void)hipLaunchCooperativeKernel((const void*)rnn_layer, dim3(NWG), dim3(768),
                                         args, 0, stream);
    }
    // ---- layer 1 ----
    gemm_xp<<<dim3(24, 128), 256, 0, stream>>>(h1s, Wxb + 3145728, bx + R3H, xp);
    {
        const unsigned short* a0 = Whb + 3145728;
        const unsigned short* a1 = xp;
        const float* a2 = prevh + BH;
        const float* a3 = bh + R3H;
        unsigned short* a4 = hb0;
        unsigned short* a5 = hb1;
        unsigned short* a6 = h1s;
        float* a7 = out;                  // last_layer_hiddens
        float* a8 = out + BTH + BH;       // last_step layer 1
        unsigned* a9 = flg;
        unsigned a10 = 130u;
        int a11 = 1;
        void* args[] = {&a0, &a1, &a2, &a3, &a4, &a5, &a6, &a7, &a8, &a9, &a10, &a11};
        (void)hipLaunchCooperativeKernel((const void*)rnn_layer, dim3(NWG), dim3(768),
                                         args, 0, stream);
    }
}